// Round 7
// baseline (2325.056 us; speedup 1.0000x reference)
//
#include <hip/hip_runtime.h>
#include <math.h>

// DynamiSE: GCN + 2x RK4 neural ODE + combine/LN.
// R1: CSR gather, coef folded into matmul (hs = dinv * x@W).
// R2: mm32 fused into agg epilogue, hs double-buffered.
// R3: merged pos/neg dispatch.
// R4: fp16 hs (64B gather rows). FAILED replay (read-before-write of poison).
// R5: blanket memset(0) of used ws every call (determinism insurance; keep!).
// R6: dense-write CSR build (bucket staging, 2 passes; write traffic 315->~40MB)
//     with fill4 fallback; agg_stage drops sidx LDS staging (quad lanes
//     broadcast-read csr) -> 13.3KB LDS, 8 blocks/CU.

#define TPB 256
#define SCAN_T 1024
#define RB 512        // max radix buckets (keys >> 10)
#define PA_TILE 4096  // edges per passA block (16/thread)

typedef _Float16 h8 __attribute__((ext_vector_type(8)));
typedef float f8 __attribute__((ext_vector_type(8)));

// ---------- CSR build ----------

struct SegG { const int* src; const int* dst; int n; int goff; };
struct FSeg { const int* src; const int* dst; int n; const int* offs; int* cur; };

__global__ void count4(SegG s0, SegG s1, SegG s2, SegG s3, int* __restrict__ cnt3) {
    int i = blockIdx.x * blockDim.x + threadIdx.x;
    SegG s; int e;
    if (i < s0.n) { s = s0; e = i; }
    else if (i < s0.n + s1.n) { s = s1; e = i - s0.n; }
    else if (i < s0.n + s1.n + s2.n) { s = s2; e = i - s0.n - s1.n; }
    else if (i < s0.n + s1.n + s2.n + s3.n) { s = s3; e = i - s0.n - s1.n - s2.n; }
    else return;
    atomicAdd(&cnt3[s.goff + s.dst[e]], 1);
}

// fallback fill (R5-proven)
__global__ void fill4(FSeg s0, FSeg s1, FSeg s2, FSeg s3, int* __restrict__ csr) {
    int i = blockIdx.x * blockDim.x + threadIdx.x;
    FSeg s; int e;
    if (i < s0.n) { s = s0; e = i; }
    else if (i < s0.n + s1.n) { s = s1; e = i - s0.n; }
    else if (i < s0.n + s1.n + s2.n) { s = s2; e = i - s0.n - s1.n; }
    else if (i < s0.n + s1.n + s2.n + s3.n) { s = s3; e = i - s0.n - s1.n - s2.n; }
    else return;
    int d = s.dst[e];
    int pos = s.offs[d] + atomicAdd(&s.cur[d], 1);
    csr[pos] = s.src[e];
}

__global__ void dinv_from_cnt(const int* __restrict__ cnt, float* __restrict__ dinv, int n) {
    int i = blockIdx.x * blockDim.x + threadIdx.x;
    if (i < n) dinv[i] = rsqrtf(1.0f + (float)cnt[i]);
}

__global__ void scan_block(const int* __restrict__ in, int n, int* __restrict__ out,
                           int* __restrict__ bsums) {
    __shared__ int sh[SCAN_T];
    int tx = threadIdx.x;
    int g = blockIdx.x * SCAN_T + tx;
    int v = (g < n) ? in[g] : 0;
    sh[tx] = v;
    __syncthreads();
    for (int off = 1; off < SCAN_T; off <<= 1) {
        int t = (tx >= off) ? sh[tx - off] : 0;
        __syncthreads();
        sh[tx] += t;
        __syncthreads();
    }
    if (g < n) out[g] = sh[tx] - v; // exclusive
    if (tx == SCAN_T - 1) bsums[blockIdx.x] = sh[tx];
}

__global__ void scan_sums(int* __restrict__ bsums, int nb) {
    __shared__ int sh[SCAN_T];
    int tx = threadIdx.x;
    int v = (tx < nb) ? bsums[tx] : 0;
    sh[tx] = v;
    __syncthreads();
    for (int off = 1; off < SCAN_T; off <<= 1) {
        int t = (tx >= off) ? sh[tx - off] : 0;
        __syncthreads();
        sh[tx] += t;
        __syncthreads();
    }
    if (tx < nb) bsums[tx] = sh[tx] - v;
}

__global__ void scan_add(int* __restrict__ offs, const int* __restrict__ bsums, int n, int total) {
    int g = blockIdx.x * blockDim.x + threadIdx.x;
    if (g < n) offs[g] += bsums[g >> 10]; // SCAN_T=1024 partitioning
    if (g == 0) offs[n] = total;
}

__global__ void init_stage_cur(const int* __restrict__ offs3, int* __restrict__ stage_cur,
                               int B, int n3) {
    int b = blockIdx.x * blockDim.x + threadIdx.x;
    if (b < B) {
        int k = b << 10; if (k > n3) k = n3;
        stage_cur[b] = offs3[k];
    }
}

// passA: bucket-staged scatter. staging layout mirrors csr3 bucket spans.
__global__ __launch_bounds__(TPB) void passA(SegG s0, SegG s1, SegG s2, SegG s3,
                                             int* __restrict__ stage_cur,
                                             int* __restrict__ staging, int Etot) {
    __shared__ int lh[RB];
    __shared__ int lbase[RB];
    int tid = threadIdx.x;
    int base = blockIdx.x * PA_TILE;
    int t1 = s0.n, t2 = t1 + s1.n, t3 = t2 + s2.n;

    for (int b = tid; b < RB; b += TPB) lh[b] = 0;
    __syncthreads();

    int gds[16], srcs[16];
#pragma unroll
    for (int k = 0; k < 16; ++k) {
        int i = base + k * TPB + tid;
        gds[k] = -1;
        if (i < Etot) {
            SegG s; int e;
            if (i < t1) { s = s0; e = i; }
            else if (i < t2) { s = s1; e = i - t1; }
            else if (i < t3) { s = s2; e = i - t2; }
            else { s = s3; e = i - t3; }
            int gd = s.goff + s.dst[e];
            gds[k] = gd;
            srcs[k] = s.src[e];
            atomicAdd(&lh[gd >> 10], 1);
        }
    }
    __syncthreads();
    for (int b = tid; b < RB; b += TPB) {
        int c = lh[b];
        lbase[b] = c ? atomicAdd(&stage_cur[b], c) : 0;
    }
    __syncthreads();
    for (int b = tid; b < RB; b += TPB) lh[b] = 0;
    __syncthreads();
#pragma unroll
    for (int k = 0; k < 16; ++k) {
        int gd = gds[k];
        if (gd >= 0) {
            int b = gd >> 10;
            int r = atomicAdd(&lh[b], 1);
            staging[lbase[b] + r] = ((gd & 1023) << 17) | srcs[k];
        }
    }
}

// passB: per-(bucket,slice) final placement within L2-resident bucket window.
__global__ __launch_bounds__(TPB) void passB(const int* __restrict__ staging,
                                             const int* __restrict__ offs3,
                                             int* __restrict__ cur3,
                                             int* __restrict__ csr3, int n3) {
    int b = blockIdx.x >> 3, sl = blockIdx.x & 7;
    int k0 = b << 10;
    int k1 = k0 + 1024; if (k1 > n3) k1 = n3;
    if (k0 >= n3) return;
    int lo = offs3[k0], hi = offs3[k1];
    int len = hi - lo;
    int c0 = lo + (int)((long long)len * sl / 8);
    int c1 = lo + (int)((long long)len * (sl + 1) / 8);
    for (int i = c0 + threadIdx.x; i < c1; i += TPB) {
        int ent = staging[i];
        int gd = k0 + (ent >> 17);
        int pos = offs3[gd] + atomicAdd(&cur3[gd], 1);
        csr3[pos] = ent & 0x1FFFF;
    }
}

// ---------- seed matmuls: hs16 = fp16(dinv * (x @ W)) ----------

__global__ void mm32_kernel(const float* __restrict__ x, const float* __restrict__ W,
                            const float* __restrict__ dinv, _Float16* __restrict__ hs, int N) {
    __shared__ float Ws[32][32];
    __shared__ float xs[8][32];
    int tid = threadIdx.x;
    for (int i = tid; i < 32 * 32; i += TPB) Ws[i >> 5][i & 31] = W[i];
    int base = blockIdx.x * 8;
    {
        int idx = base * 32 + tid;
        xs[tid >> 5][tid & 31] = (idx < N * 32) ? x[idx] : 0.0f;
    }
    __syncthreads();
    int row = tid >> 5, c = tid & 31;
    int gr = base + row;
    float acc = 0.0f;
#pragma unroll
    for (int k = 0; k < 32; ++k) acc += xs[row][k] * Ws[k][c];
    if (gr < N) hs[gr * 32 + c] = (_Float16)(acc * dinv[gr]);
}

__global__ void mm128_kernel(const float* __restrict__ x, const float* __restrict__ W,
                             const float* __restrict__ dinv, _Float16* __restrict__ hs, int N) {
    __shared__ float Ws[128][32]; // 16 KB
    __shared__ float xs[8][128];  // 4 KB
    int tid = threadIdx.x;
    for (int i = tid; i < 128 * 32; i += TPB) Ws[i >> 5][i & 31] = W[i];
    int base = blockIdx.x * 8;
    for (int i = tid; i < 8 * 128; i += TPB) {
        int idx = base * 128 + i;
        xs[i >> 7][i & 127] = (idx < N * 128) ? x[idx] : 0.0f;
    }
    __syncthreads();
    int row = tid >> 5, c = tid & 31;
    int gr = base + row;
    float acc = 0.0f;
#pragma unroll
    for (int k = 0; k < 128; ++k) acc += xs[row][k] * Ws[k][c];
    if (gr < N) hs[gr * 32 + c] = (_Float16)(acc * dinv[gr]);
}

// ---------- fused CSR aggregate + RK4 stage + next matmul ----------

struct Job {
    const int* offs; const int* csr;
    const _Float16* hs_in; _Float16* hs_out;
    const float* dinv; const float* dinv_next;
    const float* bias; const float* wt;
    float* ksum; float* x;
    const float* W;
};

// 4 lanes/node (8 channels each), 64 nodes/block. blocks [0,nbp) -> jp else jn.
__global__ __launch_bounds__(TPB) void agg_stage(Job jp, Job jn, int nbp, float t,
                                                 int stage, int do_mm, float* __restrict__ x2,
                                                 int N) {
    __shared__ float Ws[32][32];  // 4 KB
    __shared__ float xts[64][36]; // 9 KB (stride 36)
    __shared__ int soffs[65];

    bool isP = blockIdx.x < nbp;
    const Job& J = isP ? jp : jn;
    int bid = isP ? blockIdx.x : (blockIdx.x - nbp);
    int nbase = bid * 64;
    int tid = threadIdx.x;
    int lnode = tid >> 2, q = tid & 3;
    int node = nbase + lnode;
    bool valid = node < N;

    if (do_mm) {
        for (int i = tid; i < 32 * 32; i += TPB) Ws[i >> 5][i & 31] = J.W[i];
    }
    if (tid < 65) {
        int ix = nbase + tid; if (ix > N) ix = N;
        soffs[tid] = J.offs[ix];
    }
    __syncthreads();

    f8 xrow;
#pragma unroll
    for (int j = 0; j < 8; ++j) xrow[j] = 0.f;

    if (valid) {
        const h8* hsv = (const h8*)J.hs_in;
        const int* __restrict__ csr = J.csr;
        int r0 = soffs[lnode], r1 = soffs[lnode + 1];
        f8 acc = __builtin_convertvector(hsv[node * 4 + q], f8); // self-loop
        int i = r0;
        for (; i + 4 <= r1; i += 4) {
            // quad lanes read the same csr addresses -> broadcast-coalesced
            int s0 = csr[i], s1 = csr[i + 1], s2 = csr[i + 2], s3 = csr[i + 3];
            h8 v0 = hsv[s0 * 4 + q];
            h8 v1 = hsv[s1 * 4 + q];
            h8 v2 = hsv[s2 * 4 + q];
            h8 v3 = hsv[s3 * 4 + q];
            acc += (__builtin_convertvector(v0, f8) + __builtin_convertvector(v1, f8))
                 + (__builtin_convertvector(v2, f8) + __builtin_convertvector(v3, f8));
        }
        for (; i < r1; ++i)
            acc += __builtin_convertvector(hsv[csr[i] * 4 + q], f8);

        float dv = J.dinv[node];
        f8 bb = ((const f8*)J.bias)[q];
        f8 kv;
#pragma unroll
        for (int j = 0; j < 8; ++j) kv[j] = fmaxf(acc[j] * dv + bb[j], 0.f);
        if (J.wt) {
            f8 w = ((const f8*)J.wt)[q];
#pragma unroll
            for (int j = 0; j < 8; ++j) kv[j] *= 1.f / (1.f + expf(-t * w[j]));
        }
        int idx = node * 4 + q;
        f8* x8 = (f8*)J.x;
        f8* ks8 = (f8*)J.ksum;
        if (stage == 0) {
            x8[idx] = kv;
            ((f8*)x2)[idx] = kv;
            xrow = kv;
        } else if (stage == 4) {
            f8 ks = ks8[idx];
            f8 xv = x8[idx];
            const float cc = 0.1f / 6.0f;
#pragma unroll
            for (int j = 0; j < 8; ++j) xv[j] += cc * (ks[j] + kv[j]);
            x8[idx] = xv;
            xrow = xv;
        } else {
            float a = (stage == 3) ? 0.1f : 0.05f;
            f8 xv = x8[idx];
#pragma unroll
            for (int j = 0; j < 8; ++j) xrow[j] = xv[j] + a * kv[j];
            if (stage == 1) {
                ks8[idx] = kv;
            } else {
                f8 ks = ks8[idx];
#pragma unroll
                for (int j = 0; j < 8; ++j) ks[j] += 2.f * kv[j];
                ks8[idx] = ks;
            }
        }
    }

    if (do_mm) {
        if (valid) {
#pragma unroll
            for (int j = 0; j < 8; ++j) xts[lnode][q * 8 + j] = xrow[j];
        }
        __syncthreads();
        if (valid) {
            f8 accm;
#pragma unroll
            for (int j = 0; j < 8; ++j) accm[j] = 0.f;
#pragma unroll
            for (int k = 0; k < 32; ++k) {
                float xv = xts[lnode][k];
                f8 w = *(const f8*)&Ws[k][q * 8];
                accm += xv * w;
            }
            accm *= J.dinv_next[node];
            ((h8*)J.hs_out)[node * 4 + q] = __builtin_convertvector(accm, h8);
        }
    }
}

// ---------- combine + layernorm ----------

__global__ void combine_kernel(const float* __restrict__ zp, const float* __restrict__ zn,
                               const float* __restrict__ Wc, const float* __restrict__ bc,
                               const float* __restrict__ g, const float* __restrict__ be,
                               float* __restrict__ out, int N) {
    __shared__ float Ws[64][32];
    __shared__ float zs[8][64];
    int tid = threadIdx.x;
    for (int i = tid; i < 64 * 32; i += TPB) Ws[i >> 5][i & 31] = Wc[i];
    int base = blockIdx.x * 8;
    {
        int r = tid >> 5, c = tid & 31;
        int gr = base + r;
        zs[r][c] = (gr < N) ? zp[gr * 32 + c] : 0.0f;
        zs[r][32 + c] = (gr < N) ? zn[gr * 32 + c] : 0.0f;
    }
    __syncthreads();
    int row = tid >> 5, c = tid & 31;
    int gr = base + row;
    float acc = bc[c];
#pragma unroll
    for (int k = 0; k < 64; ++k) acc += zs[row][k] * Ws[k][c];
    float s = acc, sq = acc * acc;
#pragma unroll
    for (int off = 16; off; off >>= 1) {
        s += __shfl_xor(s, off, 32);
        sq += __shfl_xor(sq, off, 32);
    }
    float mu = s * (1.0f / 32.0f);
    float var = sq * (1.0f / 32.0f) - mu * mu;
    float y = (acc - mu) * rsqrtf(var + 1e-5f) * g[c] + be[c];
    if (gr < N) out[gr * 32 + c] = y;
}

// ---------- host orchestration ----------

extern "C" void kernel_launch(void* const* d_in, const int* in_sizes, int n_in,
                              void* d_out, int out_size, void* d_ws, size_t ws_size,
                              hipStream_t stream) {
    const float* H_t = (const float*)d_in[0];
    const int* Apos = (const int*)d_in[1];
    const int* Aneg = (const int*)d_in[2];
    const int* dApos = (const int*)d_in[3];
    const int* dAneg = (const int*)d_in[4];
    const float* W_init = (const float*)d_in[5];
    const float* b_init = (const float*)d_in[6];
    const float* W_pos = (const float*)d_in[7];
    const float* b_pos = (const float*)d_in[8];
    const float* wt_pos = (const float*)d_in[9];
    const float* W_neg = (const float*)d_in[10];
    const float* b_neg = (const float*)d_in[11];
    const float* wt_neg = (const float*)d_in[12];
    const float* W_comb = (const float*)d_in[13];
    const float* b_comb = (const float*)d_in[14];
    const float* ln_g = (const float*)d_in[15];
    const float* ln_b = (const float*)d_in[16];

    const int N = in_sizes[0] / 128;
    const int E1 = in_sizes[1] / 2;
    const int E2 = in_sizes[2] / 2;
    const int DE1 = in_sizes[3] / 2;
    const int DE2 = in_sizes[4] / 2;
    const int Etot = E1 + E2 + DE1 + DE2;

    const int* Apos_src = Apos, * Apos_dst = Apos + E1;
    const int* Aneg_src = Aneg, * Aneg_dst = Aneg + E2;
    const int* dApos_src = dApos, * dApos_dst = dApos + DE1;
    const int* dAneg_src = dAneg, * dAneg_dst = dAneg + DE2;

    const size_t n32 = (size_t)N * 32;
    const size_t szf = n32 * 4;
    const size_t szh = n32 * 2;
    auto al = [](size_t b) { return (b + 255) & ~(size_t)255; };

    size_t small_bytes = 3 * al((size_t)(3 * N) * 4)      /* dinv3, cnt3, cur3 */
                       + al((3 * (size_t)N + 1) * 4)      /* offs3 */
                       + al((size_t)Etot * 4)             /* csr3 */
                       + al(SCAN_T * 4);                  /* bsums */
    size_t need_merged = 4 * al(szf) + 4 * al(szh) + small_bytes;
    size_t need_radix = need_merged + al((size_t)Etot * 4) + al(RB * 4);
    bool merged = ws_size >= need_merged + 4096;
    bool radix = merged && (ws_size >= need_radix + 4096) && (N <= 131071)
                 && (((3 * N + 1023) >> 10) <= RB);

    char* p = (char*)d_ws;
    auto alloc = [&](size_t bytes) -> void* {
        void* r = (void*)p;
        p += al(bytes);
        return r;
    };
    float* x_pos = (float*)alloc(szf);
    float* x_neg = (float*)alloc(szf);
    float* ksum_p = (float*)alloc(szf);
    float* ksum_n = merged ? (float*)alloc(szf) : ksum_p;
    _Float16* hs_pa = (_Float16*)alloc(szh);
    _Float16* hs_pb = (_Float16*)alloc(szh);
    _Float16* hs_na = merged ? (_Float16*)alloc(szh) : hs_pa;
    _Float16* hs_nb = merged ? (_Float16*)alloc(szh) : hs_pb;
    float* dinv3 = (float*)alloc((size_t)(3 * N) * 4);
    int* cnt3 = (int*)alloc((size_t)(3 * N) * 4);
    int* cur3 = (int*)alloc((size_t)(3 * N) * 4);
    int* offs3 = (int*)alloc((3 * (size_t)N + 1) * 4);
    int* csr3 = (int*)alloc((size_t)Etot * 4);
    int* bsums = (int*)alloc(SCAN_T * 4);
    int* staging = radix ? (int*)alloc((size_t)Etot * 4) : nullptr;
    int* stage_cur = radix ? (int*)alloc(RB * 4) : nullptr;

    size_t used = (size_t)(p - (char*)d_ws);
    if (used > ws_size) used = ws_size;

    // R5: blanket zero of every used ws byte — deterministic initial state
    // on every call/replay (harness poisons ws with 0xAA). Keep this.
    hipMemsetAsync(d_ws, 0, used, stream);

    float* dinv_all = dinv3, * dinv_pos = dinv3 + N, * dinv_neg = dinv3 + 2 * N;
    const int* offs_all = offs3, * offs_pos = offs3 + N, * offs_neg = offs3 + 2 * N;

    dim3 blk(TPB);
    auto gblk = [](int n) { return dim3((n + TPB - 1) / TPB); };
    dim3 grid_rows((N + 7) / 8);
    const int nb64 = (N + 63) / 64;
    const int n3 = 3 * N;
    const int nbs = (n3 + SCAN_T - 1) / SCAN_T;
    const int B = (n3 + 1023) >> 10;

    // ---- fused CSR build for all 3 graphs ----
    SegG s0 = { Apos_src, Apos_dst, E1, 0 };
    SegG s1 = { Aneg_src, Aneg_dst, E2, 0 };
    SegG s2 = { dApos_src, dApos_dst, DE1, N };
    SegG s3 = { dAneg_src, dAneg_dst, DE2, 2 * N };
    count4<<<gblk(Etot), blk, 0, stream>>>(s0, s1, s2, s3, cnt3);
    dinv_from_cnt<<<gblk(n3), blk, 0, stream>>>(cnt3, dinv3, n3);
    scan_block<<<nbs, SCAN_T, 0, stream>>>(cnt3, n3, offs3, bsums);
    scan_sums<<<1, SCAN_T, 0, stream>>>(bsums, nbs);
    scan_add<<<gblk(n3), blk, 0, stream>>>(offs3, bsums, n3, Etot);
    if (radix) {
        init_stage_cur<<<gblk(B), blk, 0, stream>>>(offs3, stage_cur, B, n3);
        passA<<<(Etot + PA_TILE - 1) / PA_TILE, blk, 0, stream>>>(s0, s1, s2, s3,
                                                                  stage_cur, staging, Etot);
        passB<<<B * 8, blk, 0, stream>>>(staging, offs3, cur3, csr3, n3);
    } else {
        FSeg f0 = { Apos_src, Apos_dst, E1, offs3, cur3 };
        FSeg f1 = { Aneg_src, Aneg_dst, E2, offs3, cur3 };
        FSeg f2 = { dApos_src, dApos_dst, DE1, offs3 + N, cur3 + N };
        FSeg f3 = { dAneg_src, dAneg_dst, DE2, offs3 + 2 * N, cur3 + 2 * N };
        fill4<<<gblk(Etot), blk, 0, stream>>>(f0, f1, f2, f3, csr3);
    }

    // ---- job descriptors ----
    auto mkjob = [&](const int* offs, const _Float16* hs_in, _Float16* hs_out,
                     const float* dinv, const float* dinv_next, const float* bias,
                     const float* wt, float* ksum, float* x, const float* W) {
        Job j; j.offs = offs; j.csr = csr3; j.hs_in = hs_in; j.hs_out = hs_out;
        j.dinv = dinv; j.dinv_next = dinv_next; j.bias = bias; j.wt = wt;
        j.ksum = ksum; j.x = x; j.W = W; return j;
    };

    // ---- init GCN: H0 = relu(gcn(H_t)) -> x_pos, x_neg; epilogue seeds pos hs ----
    mm128_kernel<<<grid_rows, blk, 0, stream>>>(H_t, W_init, dinv_all, hs_pa, N);
    {
        Job j0 = mkjob(offs_all, hs_pa, hs_pb, dinv_all, dinv_pos, b_init,
                       nullptr, nullptr, x_pos, W_pos);
        agg_stage<<<nb64, blk, 0, stream>>>(j0, j0, nb64, 0.0f, 0, 1, x_neg, N);
    }

    if (merged) {
        mm32_kernel<<<grid_rows, blk, 0, stream>>>(x_neg, W_neg, dinv_neg, hs_nb, N);
        for (int s = 0; s < 10; ++s) {
            float t0 = 0.1f * (float)s;
            int last_mm = (s == 9) ? 0 : 1;
            Job p1 = mkjob(offs_pos, hs_pb, hs_pa, dinv_pos, dinv_pos, b_pos, wt_pos, ksum_p, x_pos, W_pos);
            Job n1 = mkjob(offs_neg, hs_nb, hs_na, dinv_neg, dinv_neg, b_neg, wt_neg, ksum_n, x_neg, W_neg);
            agg_stage<<<2 * nb64, blk, 0, stream>>>(p1, n1, nb64, t0, 1, 1, nullptr, N);
            Job p2 = p1; p2.hs_in = hs_pa; p2.hs_out = hs_pb;
            Job n2 = n1; n2.hs_in = hs_na; n2.hs_out = hs_nb;
            agg_stage<<<2 * nb64, blk, 0, stream>>>(p2, n2, nb64, t0 + 0.05f, 2, 1, nullptr, N);
            agg_stage<<<2 * nb64, blk, 0, stream>>>(p1, n1, nb64, t0 + 0.05f, 3, 1, nullptr, N);
            agg_stage<<<2 * nb64, blk, 0, stream>>>(p2, n2, nb64, t0 + 0.1f, 4, last_mm, nullptr, N);
        }
    } else {
        for (int ode = 0; ode < 2; ++ode) {
            float* x = ode ? x_neg : x_pos;
            const float* W = ode ? W_neg : W_pos;
            const float* b = ode ? b_neg : b_pos;
            const float* wt = ode ? wt_neg : wt_pos;
            const float* dinv = ode ? dinv_neg : dinv_pos;
            const int* offs = ode ? offs_neg : offs_pos;
            if (ode == 1) {
                mm32_kernel<<<grid_rows, blk, 0, stream>>>(x, W, dinv, hs_pb, N);
            }
            for (int s = 0; s < 10; ++s) {
                float t0 = 0.1f * (float)s;
                int last_mm = (s == 9) ? 0 : 1;
                Job j1 = mkjob(offs, hs_pb, hs_pa, dinv, dinv, b, wt, ksum_p, x, W);
                Job j2 = j1; j2.hs_in = hs_pa; j2.hs_out = hs_pb;
                agg_stage<<<nb64, blk, 0, stream>>>(j1, j1, nb64, t0, 1, 1, nullptr, N);
                agg_stage<<<nb64, blk, 0, stream>>>(j2, j2, nb64, t0 + 0.05f, 2, 1, nullptr, N);
                agg_stage<<<nb64, blk, 0, stream>>>(j1, j1, nb64, t0 + 0.05f, 3, 1, nullptr, N);
                agg_stage<<<nb64, blk, 0, stream>>>(j2, j2, nb64, t0 + 0.1f, 4, last_mm, nullptr, N);
            }
        }
    }

    // ---- combine + layernorm ----
    combine_kernel<<<grid_rows, blk, 0, stream>>>(x_pos, x_neg, W_comb, b_comb, ln_g, ln_b,
                                                  (float*)d_out, N);
}